// Round 2
// baseline (3034.607 us; speedup 1.0000x reference)
//
#include <hip/hip_runtime.h>

// ============================================================================
// fp32 I/O. V2 restructure on top of the 2530us baseline:
//  - 5 balanced block types interleaved %5: P0 (out 0e, 41k FMA),
//    P1a/P1b (out 1o w-halves, ~89k each), P2a/P2b (out 2e w-halves, ~65k)
//  - x register-tiling: 011+121 share a q-tile (vq[12]); 022 b-tile (tt[20]);
//    112 u-tile of 2 (r2[30]); bodies 200-400 FMA per hoisted load batch
//  - weights re-laid in prep3 to match tiled consumption (linear streams)
//  - smaller acc arrays (48/40) -> VGPR <=128 -> 4 waves/SIMD
//
// ws float layout:
//   [0,363)    w3j tables
//   [512,...)  merged/symmetrized weights (see OFF_*)
//   byte 1MB.. x-transpose [208][N]
// ============================================================================
#define T000 0
#define T011 1
#define T101 10
#define T110 19
#define T022 28
#define T202 53
#define T220 78
#define T121 103
#define T211 148
#define T112 193
#define T222 238
#define NTAB 363

// source tp_w offsets (verified: total 208896)
#define TP000 0
#define TP011 32768
#define TP022 65536
#define TP101 73728
#define TP110 106496
#define TP112 139264
#define TP121 155648
#define TP202 172032
#define TP211 180224
#define TP220 196608
#define TP222 204800

// destination (prepared) weight offsets
#define OFF_CW000 512      // [pid528][w32]                     (unchanged)
#define OFF_CW110 17408    // [pid528][w32]                     (unchanged)
#define OFF_CW220 34304    // [pid136][w32]                     (unchanged)
#define OFF_CW011 38656    // [h2][qt8][p32][ql4][wl16]  merged 011+101
#define OFF_CW121 71424    // [h2][qt8][b16][ql4][wl16]  merged 121+211
#define OFF_CW022 87808    // [h2][bt4][p32][bl4][wl8]   merged 022+202
#define OFF_CW112 96000    // [h2][ut16-triangle][wl8]
#define OFF_CW222 104448   // [h2][pid136][wl8]
#define OFF_LIN0  106624   // [32][32]
#define OFF_LIN1  107648   // [32][32]
#define OFF_LIN2  108672   // [16][16]
#define PREP_THREADS 108416
#define XT_BYTE_OFF ((size_t)1 << 20)

// ============================================================================
// Parallel device-side Wigner 3j (literal reference math, fp64, 1 thr/element)
// ============================================================================
struct cplx { double re, im; };
__device__ inline cplx cmul(cplx a, cplx b){ return {a.re*b.re - a.im*b.im, a.re*b.im + a.im*b.re}; }

__device__ double dfact(int n){ double r=1; for(int i=2;i<=n;i++) r*=i; return r; }

__device__ double dcgc(int j1,int m1,int j2,int m2,int j3,int m3){
  if (m3 != m1+m2) return 0.0;
  double pref = sqrt((2.0*j3+1)*dfact(j3+j1-j2)*dfact(j3-j1+j2)*dfact(j1+j2-j3)/dfact(j1+j2+j3+1));
  pref *= sqrt(dfact(j3+m3)*dfact(j3-m3)*dfact(j1-m1)*dfact(j1+m1)*dfact(j2-m2)*dfact(j2+m2));
  int k0 = max(0, max(j2-j3-m1, j1-j3+m2));
  int k1 = min(j1+j2-j3, min(j1-m1, j2+m2));
  double s = 0.0;
  for(int k=k0;k<=k1;k++){
    double d = dfact(k)*dfact(j1+j2-j3-k)*dfact(j1-m1-k)*dfact(j2+m2-k)*dfact(j3-j2+m1+k)*dfact(j3-j1-m2+k);
    s += ((k&1)?-1.0:1.0)/d;
  }
  return pref*s;
}

__device__ cplx qel(int l, int a, int c){
  const double s2 = 0.7071067811865475244;
  cplx base = {0.0, 0.0};
  if (a < l){
    if (c == 2*l-a) base = {s2, 0.0};
    else if (c == a) base = {0.0, -s2};
  } else if (a == l){
    if (c == l) base = {1.0, 0.0};
  } else {
    double sgn = ((a-l)&1)? -1.0 : 1.0;
    if (c == a) base = {sgn*s2, 0.0};
    else if (c == 2*l-a) base = {0.0, sgn*s2};
  }
  cplx ph = {1.0,0.0}, mi = {0.0,-1.0};
  for(int t=0;t<l;t++) ph = cmul(ph, mi);
  return cmul(base, ph);
}

__global__ void w3j_init(float* __restrict__ ws){
  __shared__ double red[128];
  __shared__ double snorm;
  const int spec[11][4] = {
    {0,0,0,T000},{0,1,1,T011},{1,0,1,T101},{1,1,0,T110},
    {0,2,2,T022},{2,0,2,T202},{2,2,0,T220},{1,2,1,T121},
    {2,1,1,T211},{1,1,2,T112},{2,2,2,T222}};
  int tbl = blockIdx.x;
  int l1 = spec[tbl][0], l2 = spec[tbl][1], l3 = spec[tbl][2], off = spec[tbl][3];
  int n1 = 2*l1+1, n2 = 2*l2+1, n3 = 2*l3+1, nel = n1*n2*n3;
  int t = threadIdx.x;
  double val = 0.0;
  if (t < nel){
    int k = t % n3, j = (t/n3) % n2, i = t/(n3*n2);
    for(int a=0;a<n1;a++){ int m1 = a-l1;
      for(int b=0;b<n2;b++){ int m2 = b-l2, m3 = m1+m2;
        if (m3 < -l3 || m3 > l3) continue;
        double C = dcgc(l1,m1,l2,m2,l3,m3);
        if (C == 0.0) continue;
        cplx q1 = qel(l1,a,i), q2 = qel(l2,b,j), q3 = qel(l3,l3+m3,k);
        q3.im = -q3.im;
        cplx p = cmul(cmul(q1,q2), q3);
        val += p.re * C;
      }
    }
  }
  red[t] = val*val;
  __syncthreads();
  for(int s=64; s>0; s>>=1){
    if (t < s) red[t] += red[t+s];
    __syncthreads();
  }
  if (t == 0) snorm = sqrt(red[0]);
  __syncthreads();
  if (t < nel) ws[off + t] = (float)(val / snorm);
}

// ============================================================================
// Weight prep: symmetrize (u<=v) + transpose-merge + fold coeffs + tile layout
// ============================================================================
__device__ inline void pdec(int pid, int m, int& u, int& v){
  int uu = 0;
  while (pid >= m-uu){ pid -= (m-uu); uu++; }
  u = uu; v = uu + pid;
}

__global__ void prep3(const float* __restrict__ tp, const float* __restrict__ lin,
                      float* __restrict__ ws){
  const float PK0 = 1.0f/48.0f;
  const float PK1 = 1.0f/32.0f;
  const float PK2 = sqrtf(5.0f)/48.0f;
  int t = blockIdx.x*256 + threadIdx.x;
  if (t >= PREP_THREADS) return;
  if (t < 16896){                               // cw000p [pid528][w32]
    int w = t & 31, pid = t >> 5; int u,v; pdec(pid,32,u,v);
    float s = tp[TP000+(u*32+v)*32+w];
    if (u < v) s += tp[TP000+(v*32+u)*32+w];
    ws[OFF_CW000 + t] = PK0 * ws[T000] * s; return;
  }
  t -= 16896;
  if (t < 16896){                               // cw110p [pid528][w32]
    int w = t & 31, pid = t >> 5; int u,v; pdec(pid,32,u,v);
    float s = tp[TP110+(u*32+v)*32+w];
    if (u < v) s += tp[TP110+(v*32+u)*32+w];
    ws[OFF_CW110 + t] = PK0 * ws[T110] * s; return;
  }
  t -= 16896;
  if (t < 4352){                                // cw220p [pid136][w32]
    int w = t & 31, pid = t >> 5; int u,v; pdec(pid,16,u,v);
    float s = tp[TP220+(u*16+v)*32+w];
    if (u < v) s += tp[TP220+(v*16+u)*32+w];
    ws[OFF_CW220 + t] = PK0 * ws[T220] * s; return;
  }
  t -= 4352;
  if (t < 32768){                               // cw011 [h][qt][p][ql][wl16]
    int wl = t & 15, ql = (t>>4)&3, p = (t>>6)&31, qt = (t>>11)&7, h = t>>14;
    int q = 4*qt + ql, w = 16*h + wl;
    float d011 = ws[T011], d101 = ws[T101];
    float s = d011 * tp[TP011+(p*32+q)*32+w] + d101 * tp[TP101+(q*32+p)*32+w];
    ws[OFF_CW011 + t] = PK1 * s; return;
  }
  t -= 32768;
  if (t < 16384){                               // cw121 [h][qt][b][ql][wl16]
    int wl = t & 15, ql = (t>>4)&3, b = (t>>6)&15, qt = (t>>10)&7, h = t>>13;
    int q = 4*qt + ql, w = 16*h + wl;
    float s = tp[TP121+(q*16+b)*32+w] + tp[TP211+(b*32+q)*32+w];
    ws[OFF_CW121 + t] = PK1 * s; return;
  }
  t -= 16384;
  if (t < 8192){                                // cw022 [h][bt][p][bl][wl8]
    int wl = t & 7, bl = (t>>3)&3, p = (t>>5)&31, bt = (t>>10)&3, h = t>>12;
    int b = 4*bt + bl, w = 8*h + wl;
    float d022 = ws[T022], d202 = ws[T202];
    float s = d022 * tp[TP022+(p*16+b)*16+w] + d202 * tp[TP202+(b*32+p)*16+w];
    ws[OFF_CW022 + t] = PK2 * s; return;
  }
  t -= 8192;
  if (t < 8448){                                // cw112 [h][ut16-triangle][wl8]
    int h = t / 4224, r = t - 4224*h;
    int e = r >> 3, wl = r & 7, w = 8*h + wl;
    // ut sizes: 63-4*ut entries; cum(ut) = 65*ut - 2*ut*ut
    int ut = 0;
    while (ut < 15){
      int nxt = 65*(ut+1) - 2*(ut+1)*(ut+1);
      if (e >= nxt) ut++; else break;
    }
    int k = e - (65*ut - 2*ut*ut);
    int u, v;
    if (k < 3){
      if (k == 0){ u = 2*ut;         v = 2*ut;   }
      else       { u = 2*ut + (k-1); v = 2*ut+1; }
    } else {
      int k2 = k - 3;
      v = 2*ut + 2 + (k2 >> 1);
      u = 2*ut + (k2 & 1);
    }
    float s = tp[TP112+(u*32+v)*16+w];
    if (u < v) s += tp[TP112+(v*32+u)*16+w];
    ws[OFF_CW112 + t] = PK2 * s; return;
  }
  t -= 8448;
  if (t < 2176){                                // cw222 [h][pid136][wl8]
    int h = t / 1088, r = t - 1088*h;
    int pid = r >> 3, wl = r & 7, w = 8*h + wl;
    int u,v; pdec(pid,16,u,v);
    float s = tp[TP222+(u*16+v)*16+w];
    if (u < v) s += tp[TP222+(v*16+u)*16+w];
    ws[OFF_CW222 + t] = PK2 * s; return;
  }
  t -= 2176;
  if (t < 1024){ ws[OFF_LIN0 + t] = 0.17677669529663687f * lin[t]; return; }
  t -= 1024;
  if (t < 1024){ ws[OFF_LIN1 + t] = 0.17677669529663687f * lin[1024+t]; return; }
  t -= 1024;
  ws[OFF_LIN2 + t] = 0.25f * lin[2048+t];
}

// ============================================================================
// x transpose: [N][208] -> [208][N]
// ============================================================================
__global__ void transpose_kernel(const float* __restrict__ x, float* __restrict__ xt, int N){
  __shared__ float tile[64*209];
  int z0 = blockIdx.x*64;
  int nz = N - z0; if (nz > 64) nz = 64;
  for(int idx=threadIdx.x; idx<64*208; idx+=256){
    int zl = idx/208, d = idx - zl*208;
    float v = (zl < nz) ? x[(size_t)z0*208 + idx] : 0.f;
    tile[zl*209 + d] = v;
  }
  __syncthreads();
  for(int idx=threadIdx.x; idx<64*208; idx+=256){
    int d = idx>>6, zl = idx & 63;
    if (zl < nz) xt[(size_t)d*N + z0 + zl] = tile[zl*209 + d];
  }
}

// ============================================================================
// Fused 5-type main kernel: phase = blockIdx.x % 5
//   0: out 0e (w 0..31); 1/2: out 1o w-half h=phase-1; 3/4: out 2e w-half
// ============================================================================
__global__ __launch_bounds__(256, 4)
void tp_fused(const float* __restrict__ xt, const float* __restrict__ ws,
              float* __restrict__ out, int N, int NB){
  __shared__ float sT[NTAB];
  for(int i=threadIdx.x; i<NTAB; i+=256) sT[i] = ws[i];
  __syncthreads();
  int phase = blockIdx.x % 5;
  int z = (blockIdx.x / 5)*256 + threadIdx.x;
  if (z >= N) return;
  const size_t Ns = (size_t)N;
#define XT(d) xt[(size_t)(d)*Ns + z]
  float* __restrict__ oz = out + (size_t)z*208;

  if (phase == 0){
    // ---------------- out irrep 0e (32) ----------------
    float acc[32];
#pragma unroll
    for(int w=0;w<32;w++) acc[w]=0.f;
    const float* wp = ws + OFF_CW000;
#pragma unroll 1
    for(int u=0;u<32;u++){
      float su = XT(u);
#pragma unroll 1
      for(int v=u;v<32;v++){
        float p = su * XT(v);
#pragma unroll
        for(int w=0;w<32;w++) acc[w] = fmaf(p, wp[w], acc[w]);
        wp += 32;
      }
    }
    const float* lw = ws + OFF_LIN0;
#pragma unroll 1
    for(int u=0;u<32;u++){
      float su = XT(u);
#pragma unroll
      for(int w=0;w<32;w++) acc[w] = fmaf(su, lw[w], acc[w]);
      lw += 32;
    }
    wp = ws + OFF_CW110;
#pragma unroll 1
    for(int u=0;u<32;u++){
      float a0=XT(32+3*u), a1=XT(33+3*u), a2=XT(34+3*u);
#pragma unroll 1
      for(int v=u;v<32;v++){
        float p = a0*XT(32+3*v) + a1*XT(33+3*v) + a2*XT(34+3*v);
#pragma unroll
        for(int w=0;w<32;w++) acc[w] = fmaf(p, wp[w], acc[w]);
        wp += 32;
      }
    }
    wp = ws + OFF_CW220;
#pragma unroll 1
    for(int u=0;u<16;u++){
      float b0=XT(128+5*u),b1=XT(129+5*u),b2=XT(130+5*u),b3=XT(131+5*u),b4=XT(132+5*u);
#pragma unroll 1
      for(int v=u;v<16;v++){
        float p = b0*XT(128+5*v)+b1*XT(129+5*v)+b2*XT(130+5*v)+b3*XT(131+5*v)+b4*XT(132+5*v);
#pragma unroll
        for(int w=0;w<32;w++) acc[w] = fmaf(p, wp[w], acc[w]);
        wp += 32;
      }
    }
#pragma unroll
    for(int w=0;w<32;w++) oz[w] = acc[w];

  } else if (phase <= 2){
    // ---------------- out irrep 1o, w-half h (16 w x 3 comps) ----------------
    const int h = phase - 1;
    float acc[48];
#pragma unroll
    for(int i=0;i<48;i++) acc[i]=0.f;
    const float* wp011 = ws + OFF_CW011 + (h<<14);
    const float* wp121 = ws + OFF_CW121 + (h<<13);
#pragma unroll 1
    for(int qt=0; qt<8; ++qt){
      float vq[12];
#pragma unroll
      for(int j=0;j<12;j++) vq[j] = XT(32 + 12*qt + j);
      // -- 011+101 merged: weights [p][ql][wl16], streamed
#pragma unroll 1
      for(int p=0; p<32; ++p){
        float sp = XT(p);
#pragma unroll
        for(int ql=0; ql<4; ++ql){
          float p0 = sp*vq[3*ql], p1 = sp*vq[3*ql+1], p2 = sp*vq[3*ql+2];
#pragma unroll
          for(int w=0; w<16; ++w){
            float wt = wp011[ql*16+w];
            acc[3*w  ] = fmaf(p0, wt, acc[3*w  ]);
            acc[3*w+1] = fmaf(p1, wt, acc[3*w+1]);
            acc[3*w+2] = fmaf(p2, wt, acc[3*w+2]);
          }
        }
        wp011 += 64;
      }
      // -- 121+211 merged: weights [b][ql][wl16], streamed
#pragma unroll 1
      for(int b=0; b<16; ++b){
        float t0=XT(128+5*b), t1=XT(129+5*b), t2=XT(130+5*b), t3=XT(131+5*b), t4=XT(132+5*b);
        float q9[9];
#pragma unroll
        for(int a=0;a<3;a++)
#pragma unroll
          for(int c=0;c<3;c++){
            q9[a*3+c] = sT[T121+(a*5+0)*3+c]*t0 + sT[T121+(a*5+1)*3+c]*t1
                      + sT[T121+(a*5+2)*3+c]*t2 + sT[T121+(a*5+3)*3+c]*t3
                      + sT[T121+(a*5+4)*3+c]*t4;
          }
#pragma unroll
        for(int ql=0; ql<4; ++ql){
          float v0=vq[3*ql], v1=vq[3*ql+1], v2=vq[3*ql+2];
          float p0 = v0*q9[0] + v1*q9[3] + v2*q9[6];
          float p1 = v0*q9[1] + v1*q9[4] + v2*q9[7];
          float p2 = v0*q9[2] + v1*q9[5] + v2*q9[8];
#pragma unroll
          for(int w=0; w<16; ++w){
            float wt = wp121[ql*16+w];
            acc[3*w  ] = fmaf(p0, wt, acc[3*w  ]);
            acc[3*w+1] = fmaf(p1, wt, acc[3*w+1]);
            acc[3*w+2] = fmaf(p2, wt, acc[3*w+2]);
          }
        }
        wp121 += 64;
      }
    }
    const float* lw = ws + OFF_LIN1 + 16*h;
#pragma unroll 1
    for(int u=0; u<32; ++u){
      float v0=XT(32+3*u), v1=XT(33+3*u), v2=XT(34+3*u);
#pragma unroll
      for(int w=0; w<16; ++w){
        float wt = lw[w];
        acc[3*w  ] = fmaf(v0, wt, acc[3*w  ]);
        acc[3*w+1] = fmaf(v1, wt, acc[3*w+1]);
        acc[3*w+2] = fmaf(v2, wt, acc[3*w+2]);
      }
      lw += 32;
    }
#pragma unroll
    for(int i=0;i<48;i++) oz[32 + 48*h + i] = acc[i];

  } else {
    // ---------------- out irrep 2e, w-half h (8 w x 5 comps) ----------------
    const int h = phase - 3;
    float acc[40];
#pragma unroll
    for(int i=0;i<40;i++) acc[i]=0.f;
    // -- 022+202 merged: b-tile of 4, weights [bt][p][bl][wl8]
    const float* wp = ws + OFF_CW022 + (h<<12);
#pragma unroll 1
    for(int bt=0; bt<4; ++bt){
      float tt[20];
#pragma unroll
      for(int j=0;j<20;j++) tt[j] = XT(128 + 20*bt + j);
#pragma unroll 1
      for(int p=0; p<32; ++p){
        float sp = XT(p);
#pragma unroll
        for(int bl=0; bl<4; ++bl){
          float p0=sp*tt[5*bl], p1=sp*tt[5*bl+1], p2=sp*tt[5*bl+2], p3=sp*tt[5*bl+3], p4=sp*tt[5*bl+4];
#pragma unroll
          for(int w=0; w<8; ++w){
            float wt = wp[bl*8+w];
            acc[5*w  ] = fmaf(p0, wt, acc[5*w  ]);
            acc[5*w+1] = fmaf(p1, wt, acc[5*w+1]);
            acc[5*w+2] = fmaf(p2, wt, acc[5*w+2]);
            acc[5*w+3] = fmaf(p3, wt, acc[5*w+3]);
            acc[5*w+4] = fmaf(p4, wt, acc[5*w+4]);
          }
        }
        wp += 32;
      }
    }
    // -- 222: weights [pid136][wl8]
    wp = ws + OFF_CW222 + h*1088;
#pragma unroll 1
    for(int u=0; u<16; ++u){
      float tu[5];
#pragma unroll
      for(int j=0;j<5;j++) tu[j]=XT(128+5*u+j);
      float r[25];
#pragma unroll
      for(int b=0;b<5;b++)
#pragma unroll
        for(int c=0;c<5;c++){
          float s=0.f;
#pragma unroll
          for(int a=0;a<5;a++) s = fmaf(sT[T222+(a*5+b)*5+c], tu[a], s);
          r[b*5+c]=s;
        }
#pragma unroll 1
      for(int v=u; v<16; ++v){
        float s0=XT(128+5*v),s1=XT(129+5*v),s2=XT(130+5*v),s3=XT(131+5*v),s4=XT(132+5*v);
        float p[5];
#pragma unroll
        for(int c=0;c<5;c++) p[c] = s0*r[c]+s1*r[5+c]+s2*r[10+c]+s3*r[15+c]+s4*r[20+c];
#pragma unroll
        for(int w=0; w<8; ++w){
          float wt = wp[w];
#pragma unroll
          for(int c=0;c<5;c++) acc[5*w+c] = fmaf(p[c], wt, acc[5*w+c]);
        }
        wp += 8;
      }
    }
    // -- lin2
    const float* lw = ws + OFF_LIN2 + 8*h;
#pragma unroll 1
    for(int u=0; u<16; ++u){
      float t0=XT(128+5*u),t1=XT(129+5*u),t2=XT(130+5*u),t3=XT(131+5*u),t4=XT(132+5*u);
#pragma unroll
      for(int w=0; w<8; ++w){
        float wt = lw[w];
        acc[5*w  ] = fmaf(t0, wt, acc[5*w  ]);
        acc[5*w+1] = fmaf(t1, wt, acc[5*w+1]);
        acc[5*w+2] = fmaf(t2, wt, acc[5*w+2]);
        acc[5*w+3] = fmaf(t3, wt, acc[5*w+3]);
        acc[5*w+4] = fmaf(t4, wt, acc[5*w+4]);
      }
      lw += 16;
    }
    // -- 112: u-tile of 2, weights [ut][v][ul][wl8] triangular
    wp = ws + OFF_CW112 + h*4224;
#pragma unroll 1
    for(int ut=0; ut<16; ++ut){
      float uu[6];
#pragma unroll
      for(int j=0;j<6;j++) uu[j] = XT(32 + 6*ut + j);
      float r2[30];
#pragma unroll
      for(int ul=0; ul<2; ++ul)
#pragma unroll
        for(int b=0;b<3;b++)
#pragma unroll
          for(int c=0;c<5;c++)
            r2[ul*15+b*5+c] = sT[T112+(0*3+b)*5+c]*uu[3*ul]
                            + sT[T112+(1*3+b)*5+c]*uu[3*ul+1]
                            + sT[T112+(2*3+b)*5+c]*uu[3*ul+2];
      // head: (u=2ut,v=2ut), (u=2ut,v=2ut+1), (u=2ut+1,v=2ut+1)
      {
        float p[5];
#pragma unroll
        for(int c=0;c<5;c++) p[c] = uu[0]*r2[c] + uu[1]*r2[5+c] + uu[2]*r2[10+c];
#pragma unroll
        for(int w=0;w<8;w++){ float wt = wp[w];
#pragma unroll
          for(int c=0;c<5;c++) acc[5*w+c] = fmaf(p[c], wt, acc[5*w+c]); }
        wp += 8;
#pragma unroll
        for(int c=0;c<5;c++) p[c] = uu[3]*r2[c] + uu[4]*r2[5+c] + uu[5]*r2[10+c];
#pragma unroll
        for(int w=0;w<8;w++){ float wt = wp[w];
#pragma unroll
          for(int c=0;c<5;c++) acc[5*w+c] = fmaf(p[c], wt, acc[5*w+c]); }
        wp += 8;
#pragma unroll
        for(int c=0;c<5;c++) p[c] = uu[3]*r2[15+c] + uu[4]*r2[20+c] + uu[5]*r2[25+c];
#pragma unroll
        for(int w=0;w<8;w++){ float wt = wp[w];
#pragma unroll
          for(int c=0;c<5;c++) acc[5*w+c] = fmaf(p[c], wt, acc[5*w+c]); }
        wp += 8;
      }
#pragma unroll 1
      for(int v=2*ut+2; v<32; ++v){
        float v0=XT(32+3*v), v1=XT(33+3*v), v2=XT(34+3*v);
#pragma unroll
        for(int ul=0; ul<2; ++ul){
          float p[5];
#pragma unroll
          for(int c=0;c<5;c++) p[c] = v0*r2[ul*15+c] + v1*r2[ul*15+5+c] + v2*r2[ul*15+10+c];
#pragma unroll
          for(int w=0;w<8;w++){ float wt = wp[w];
#pragma unroll
            for(int c=0;c<5;c++) acc[5*w+c] = fmaf(p[c], wt, acc[5*w+c]); }
          wp += 8;
        }
      }
    }
#pragma unroll
    for(int i=0;i<40;i++) oz[128 + 40*h + i] = acc[i];
  }
#undef XT
}

// ============================================================================
extern "C" void kernel_launch(void* const* d_in, const int* in_sizes, int n_in,
                              void* d_out, int out_size, void* d_ws, size_t ws_size,
                              hipStream_t stream) {
  const float* x   = (const float*)d_in[0];
  const float* tpw = (const float*)d_in[1];
  const float* lnw = (const float*)d_in[2];
  float* out = (float*)d_out;
  float* ws  = (float*)d_ws;
  const int N = in_sizes[0]/208;
  const int NB = (N + 255)/256;

  w3j_init<<<11, 128, 0, stream>>>(ws);
  prep3<<<(PREP_THREADS+255)/256, 256, 0, stream>>>(tpw, lnw, ws);

  float* xt = (float*)((char*)d_ws + XT_BYTE_OFF);
  transpose_kernel<<<(N+63)/64, 256, 0, stream>>>(x, xt, N);
  tp_fused<<<5*NB, 256, 0, stream>>>(xt, ws, out, N, NB);
}